// Round 2
// baseline (420.301 us; speedup 1.0000x reference)
//
#include <hip/hip_runtime.h>
#include <math.h>

#define NBATCH 16
#define NA     128
#define CH     512
#define EFEAT  30
#define RPB    8     // rows per block in the node-MLP kernel

static constexpr float SELU_ALPHA = 1.6732632423543772f;
static constexpr float SELU_SCALE = 1.0507009873554805f;

__device__ __forceinline__ float selu_f(float x) {
    // jax.nn.selu: scale * where(x>0, x, alpha*expm1(x))
    return SELU_SCALE * (x > 0.0f ? x : SELU_ALPHA * expm1f(x));
}

// Kernel 1: fused edge filter (Linear(30->512) + SELU + edge_mask) and
// neighbor aggregation:
//   h1[b,i,c] = sum_j selu(e[b,i,j,:]·fW[c,:] + fb[c]) * em[b,i,j] * h[b,j,c]
// One block handles 2 output rows (b,i). Thread t owns channels t and t+256.
// filter weights stay in registers (64 VGPR, padded 30->32 with zeros);
// e row is broadcast-read from LDS as float4.
// node_mask==0 rows are skipped entirely (their h1 is never read downstream);
// edge_mask==0 neighbors are skipped (wave-uniform branch, ~50% of edges).
__global__ __launch_bounds__(256)
void k_edge_agg(const float* __restrict__ h, const float* __restrict__ e,
                const float* __restrict__ node_mask, const float* __restrict__ edge_mask,
                const float* __restrict__ fW, const float* __restrict__ fb,
                float* __restrict__ h1)
{
    __shared__ float e_lds[NA * 32];   // padded row stride 32
    __shared__ float em_lds[NA];
    const int tid = threadIdx.x;
    const int b   = blockIdx.x >> 6;          // 64 blocks per batch (2 rows each)
    const int i0  = (blockIdx.x & 63) << 1;

    float w0[32], w1[32];
    #pragma unroll
    for (int f = 0; f < EFEAT; ++f) {
        w0[f] = fW[tid * EFEAT + f];
        w1[f] = fW[(tid + 256) * EFEAT + f];
    }
    w0[30] = w0[31] = w1[30] = w1[31] = 0.0f;
    const float b0 = fb[tid], b1 = fb[tid + 256];

    for (int ii = 0; ii < 2; ++ii) {
        const int i = i0 + ii;
        __syncthreads();   // identical barrier sequence both iterations
        const bool live = (node_mask[b * NA + i] != 0.0f);   // block-uniform
        if (!live) continue;

        const float* esrc = e + (size_t)(b * NA + i) * NA * EFEAT;
        for (int idx = tid; idx < NA * 32; idx += 256) {
            const int j = idx >> 5, f = idx & 31;
            e_lds[idx] = (f < EFEAT) ? esrc[j * EFEAT + f] : 0.0f;
        }
        if (tid < NA) em_lds[tid] = edge_mask[(size_t)(b * NA + i) * NA + tid];
        __syncthreads();

        float acc0 = 0.0f, acc1 = 0.0f;
        for (int j = 0; j < NA; ++j) {
            const float m = em_lds[j];        // wave-uniform broadcast read
            if (m == 0.0f) continue;          // uniform: ~50% of edges masked out
            const float4* ev = (const float4*)&e_lds[j * 32];
            float s0 = b0, s1 = b1;
            #pragma unroll
            for (int q = 0; q < 8; ++q) {
                const float4 v = ev[q];
                s0 += w0[4*q+0]*v.x + w0[4*q+1]*v.y + w0[4*q+2]*v.z + w0[4*q+3]*v.w;
                s1 += w1[4*q+0]*v.x + w1[4*q+1]*v.y + w1[4*q+2]*v.z + w1[4*q+3]*v.w;
            }
            const float* hp = h + (size_t)(b * NA + j) * CH;
            acc0 += selu_f(s0) * m * hp[tid];
            acc1 += selu_f(s1) * m * hp[tid + 256];
        }
        float* dst = h1 + (size_t)(b * NA + i) * CH;
        dst[tid]       = acc0;
        dst[tid + 256] = acc1;
    }
}

// Kernel 2: node MLP on z = [h | h1] (K=1024) + SELU + node_mask + residual.
//   out[r,c] = selu(sum_d z[r,d]*wW[c,d] + wb[c]) * nm[r] + h[r,c]
// One block handles RPB=8 rows; thread t owns channels t and t+256.
// z rows staged in LDS (32 KB), weights streamed as float4 (L2-resident,
// 2 MB reused by all 256 blocks). Masked rows skip all FMA work.
__global__ __launch_bounds__(256)
void k_node_mlp(const float* __restrict__ h, const float* __restrict__ h1,
                const float* __restrict__ node_mask,
                const float* __restrict__ wW, const float* __restrict__ wb,
                float* __restrict__ out)
{
    __shared__ float z_lds[RPB][2 * CH];
    __shared__ float rm_lds[RPB];
    const int tid  = threadIdx.x;
    const int row0 = blockIdx.x * RPB;

    for (int idx = tid; idx < RPB * CH; idx += 256) {
        const int r = idx >> 9, c = idx & (CH - 1);
        z_lds[r][c]      = h [(size_t)(row0 + r) * CH + c];
        z_lds[r][CH + c] = h1[(size_t)(row0 + r) * CH + c];  // poison if masked row; never used
    }
    if (tid < RPB) rm_lds[tid] = node_mask[row0 + tid];
    __syncthreads();

    float rm[RPB];
    #pragma unroll
    for (int r = 0; r < RPB; ++r) rm[r] = rm_lds[r];

    float acc0[RPB], acc1[RPB];
    #pragma unroll
    for (int r = 0; r < RPB; ++r) acc0[r] = acc1[r] = 0.0f;

    bool any = false;
    #pragma unroll
    for (int r = 0; r < RPB; ++r) any = any || (rm[r] != 0.0f);

    if (any) {
        const float* wr0 = wW + (size_t)tid * (2 * CH);
        const float* wr1 = wW + (size_t)(tid + 256) * (2 * CH);
        for (int d = 0; d < 2 * CH; d += 4) {
            const float4 wv0 = *(const float4*)&wr0[d];
            const float4 wv1 = *(const float4*)&wr1[d];
            #pragma unroll
            for (int r = 0; r < RPB; ++r) {           // static unroll: acc stays in VGPRs
                if (rm[r] != 0.0f) {
                    const float4 zv = *(const float4*)&z_lds[r][d];  // broadcast
                    acc0[r] += wv0.x*zv.x + wv0.y*zv.y + wv0.z*zv.z + wv0.w*zv.w;
                    acc1[r] += wv1.x*zv.x + wv1.y*zv.y + wv1.z*zv.z + wv1.w*zv.w;
                }
            }
        }
    }

    const float bb0 = wb[tid], bb1 = wb[tid + 256];
    #pragma unroll
    for (int r = 0; r < RPB; ++r) {
        const float hv0 = z_lds[r][tid];
        const float hv1 = z_lds[r][tid + 256];
        float o0 = hv0, o1 = hv1;                 // masked row: out = h (residual only)
        if (rm[r] != 0.0f) {
            o0 = selu_f(acc0[r] + bb0) * rm[r] + hv0;
            o1 = selu_f(acc1[r] + bb1) * rm[r] + hv1;
        }
        float* op = out + (size_t)(row0 + r) * CH;
        op[tid]       = o0;
        op[tid + 256] = o1;
    }
}

extern "C" void kernel_launch(void* const* d_in, const int* in_sizes, int n_in,
                              void* d_out, int out_size, void* d_ws, size_t ws_size,
                              hipStream_t stream)
{
    (void)in_sizes; (void)n_in; (void)out_size; (void)ws_size;
    const float* h  = (const float*)d_in[0];
    const float* e  = (const float*)d_in[1];
    const float* nm = (const float*)d_in[2];
    const float* em = (const float*)d_in[3];
    const float* fW = (const float*)d_in[4];
    const float* fb = (const float*)d_in[5];
    const float* wW = (const float*)d_in[6];
    const float* wb = (const float*)d_in[7];
    float* out = (float*)d_out;
    float* h1  = (float*)d_ws;   // 16*128*512 f32 = 4 MB scratch

    k_edge_agg<<<NBATCH * (NA / 2), 256, 0, stream>>>(h, e, nm, em, fW, fb, h1);
    k_node_mlp<<<(NBATCH * NA) / RPB, 256, 0, stream>>>(h, h1, nm, wW, wb, out);
}

// Round 3
// 250.424 us; speedup vs baseline: 1.6784x; 1.6784x over previous
//
#include <hip/hip_runtime.h>
#include <hip/hip_bf16.h>
#include <math.h>

#define NBATCH 16
#define NA     128
#define CH     512
#define EFEAT  30

typedef __attribute__((ext_vector_type(8))) short     bf16x8;
typedef __attribute__((ext_vector_type(4))) float     f32x4;
typedef __attribute__((ext_vector_type(8))) unsigned short ushort8;
typedef __attribute__((ext_vector_type(4))) unsigned short ushort4_t;

__device__ __forceinline__ float selu_f(float x) {
    // selu: scale*x (x>0) else scale*alpha*(e^x - 1). exp(x)-1 vs expm1: abs err ~1e-7, fine.
    const float SA = 1.7580993408473766f;   // scale*alpha
    float e = __expf(x);
    return x > 0.0f ? 1.0507009873554805f * x : fmaf(SA, e, -SA);
}

__device__ __forceinline__ unsigned short f2bf(float f) {
    __hip_bfloat16 h = __float2bfloat16(f);   // RNE
    return *reinterpret_cast<unsigned short*>(&h);
}

// -------------------------------------------------------------------------
// Kernel 1: fused edge filter + SELU + edge-mask + neighbor aggregation.
//   h1[b,i,c] = sum_{j: em[b,i,j]=1} selu(e[b,i,j,:]·fW[c,:] + fb[c]) * h[b,j,c]
// Emits z[b,i,:] = [bf16(h[b,i,:]) | bf16(h1[b,i,:])] for live rows only
// (dead rows: z stays 0xAA poison = tiny bf16 values; those GEMM rows are
// masked in kernel 2's epilogue, so poison never reaches the output).
// Block = 2 rows (b,i). Thread t owns channels t and t+256. Live-j list is
// ballot-compacted so the inner loop is branch-free and 4-deep unrolled:
// 8 independent h-loads in flight under 256 FMAs.
// -------------------------------------------------------------------------
__global__ __launch_bounds__(256)
void k_edge_agg(const float* __restrict__ h, const float* __restrict__ e,
                const float* __restrict__ node_mask, const float* __restrict__ edge_mask,
                const float* __restrict__ fW, const float* __restrict__ fb,
                unsigned short* __restrict__ z)
{
    __shared__ float e_lds[NA * 32];   // padded row stride 32 floats
    __shared__ int   jlist[NA];
    __shared__ int   wcnt[2];
    const int tid = threadIdx.x;
    const int b   = blockIdx.x >> 6;
    const int i0  = (blockIdx.x & 63) << 1;

    float w0[32], w1[32];
    #pragma unroll
    for (int f = 0; f < EFEAT; ++f) {
        w0[f] = fW[tid * EFEAT + f];
        w1[f] = fW[(tid + 256) * EFEAT + f];
    }
    w0[30] = w0[31] = w1[30] = w1[31] = 0.0f;
    const float b0 = fb[tid], b1 = fb[tid + 256];

    for (int ii = 0; ii < 2; ++ii) {
        const int i = i0 + ii;
        __syncthreads();                                   // uniform: guard LDS reuse
        if (node_mask[b * NA + i] == 0.0f) continue;       // block-uniform skip

        // stage e row (128 x 30 -> padded 128 x 32)
        const float* esrc = e + (size_t)(b * NA + i) * NA * EFEAT;
        for (int idx = tid; idx < NA * 32; idx += 256) {
            const int j = idx >> 5, f = idx & 31;
            e_lds[idx] = (f < EFEAT) ? esrc[j * EFEAT + f] : 0.0f;
        }
        // ballot-compact live j list (edge_mask is exactly 0 or 1)
        float myq = 0.0f; unsigned long long bl = 0;
        if (tid < NA) {
            myq = edge_mask[(size_t)(b * NA + i) * NA + tid];
            bl = __ballot(myq != 0.0f);
            if ((tid & 63) == 0) wcnt[tid >> 6] = __popcll(bl);
        }
        __syncthreads();                                   // e_lds + wcnt ready
        const int nlive = wcnt[0] + wcnt[1];
        if (tid < NA && myq != 0.0f) {
            const int base = (tid >= 64) ? wcnt[0] : 0;
            const int pos  = __popcll(bl & ((1ull << (tid & 63)) - 1));
            jlist[base + pos] = tid;
        }
        __syncthreads();                                   // jlist ready

        float acc0 = 0.0f, acc1 = 0.0f;
        int jj = 0;
        for (; jj + 4 <= nlive; jj += 4) {
            const int j0 = jlist[jj], j1 = jlist[jj+1], j2 = jlist[jj+2], j3 = jlist[jj+3];
            const float* hp0 = h + (size_t)(b * NA + j0) * CH;
            const float* hp1 = h + (size_t)(b * NA + j1) * CH;
            const float* hp2 = h + (size_t)(b * NA + j2) * CH;
            const float* hp3 = h + (size_t)(b * NA + j3) * CH;
            // issue all 8 global loads first (independent, L2-resident)
            const float ha0 = hp0[tid], hb0v = hp0[tid + 256];
            const float ha1 = hp1[tid], hb1v = hp1[tid + 256];
            const float ha2 = hp2[tid], hb2v = hp2[tid + 256];
            const float ha3 = hp3[tid], hb3v = hp3[tid + 256];
            const float4* e0 = (const float4*)&e_lds[j0 * 32];
            const float4* e1 = (const float4*)&e_lds[j1 * 32];
            const float4* e2 = (const float4*)&e_lds[j2 * 32];
            const float4* e3 = (const float4*)&e_lds[j3 * 32];
            float s00 = b0, s10 = b1, s01 = b0, s11 = b1;
            float s02 = b0, s12 = b1, s03 = b0, s13 = b1;
            #pragma unroll
            for (int q = 0; q < 8; ++q) {
                const float4 v0 = e0[q], v1 = e1[q], v2 = e2[q], v3 = e3[q];
                s00 += w0[4*q]*v0.x + w0[4*q+1]*v0.y + w0[4*q+2]*v0.z + w0[4*q+3]*v0.w;
                s10 += w1[4*q]*v0.x + w1[4*q+1]*v0.y + w1[4*q+2]*v0.z + w1[4*q+3]*v0.w;
                s01 += w0[4*q]*v1.x + w0[4*q+1]*v1.y + w0[4*q+2]*v1.z + w0[4*q+3]*v1.w;
                s11 += w1[4*q]*v1.x + w1[4*q+1]*v1.y + w1[4*q+2]*v1.z + w1[4*q+3]*v1.w;
                s02 += w0[4*q]*v2.x + w0[4*q+1]*v2.y + w0[4*q+2]*v2.z + w0[4*q+3]*v2.w;
                s12 += w1[4*q]*v2.x + w1[4*q+1]*v2.y + w1[4*q+2]*v2.z + w1[4*q+3]*v2.w;
                s03 += w0[4*q]*v3.x + w0[4*q+1]*v3.y + w0[4*q+2]*v3.z + w0[4*q+3]*v3.w;
                s13 += w1[4*q]*v3.x + w1[4*q+1]*v3.y + w1[4*q+2]*v3.z + w1[4*q+3]*v3.w;
            }
            acc0 += selu_f(s00) * ha0;  acc1 += selu_f(s10) * hb0v;
            acc0 += selu_f(s01) * ha1;  acc1 += selu_f(s11) * hb1v;
            acc0 += selu_f(s02) * ha2;  acc1 += selu_f(s12) * hb2v;
            acc0 += selu_f(s03) * ha3;  acc1 += selu_f(s13) * hb3v;
        }
        for (; jj < nlive; ++jj) {                          // remainder (<=3)
            const int j0 = jlist[jj];
            const float* hp0 = h + (size_t)(b * NA + j0) * CH;
            const float ha0 = hp0[tid], hb0v = hp0[tid + 256];
            const float4* e0 = (const float4*)&e_lds[j0 * 32];
            float s00 = b0, s10 = b1;
            #pragma unroll
            for (int q = 0; q < 8; ++q) {
                const float4 v0 = e0[q];
                s00 += w0[4*q]*v0.x + w0[4*q+1]*v0.y + w0[4*q+2]*v0.z + w0[4*q+3]*v0.w;
                s10 += w1[4*q]*v0.x + w1[4*q+1]*v0.y + w1[4*q+2]*v0.z + w1[4*q+3]*v0.w;
            }
            acc0 += selu_f(s00) * ha0;  acc1 += selu_f(s10) * hb0v;
        }

        // emit z row: [bf16(h) | bf16(h1)]
        const float* hrow = h + (size_t)(b * NA + i) * CH;
        unsigned short* zrow = z + (size_t)(b * NA + i) * (2 * CH);
        zrow[tid]            = f2bf(hrow[tid]);
        zrow[tid + 256]      = f2bf(hrow[tid + 256]);
        zrow[CH + tid]       = f2bf(acc0);
        zrow[CH + tid + 256] = f2bf(acc1);
    }
}

// -------------------------------------------------------------------------
// Kernel 2: node MLP as bf16 MFMA GEMM.  C = z (2048x1024, bf16) @ wW^T
// (512x1024, f32 converted on the fly), fused epilogue:
//   out = selu(C + wb) * node_mask + h.
// 64x64 tile, 256 blocks (1/CU), 4 waves each owning a 32x32 quadrant.
// LDS rows padded to 72 shorts (144 B = 9*16 B) -> ds_read_b128 conflicts
// reduced to benign 2-way. Masked/dead rows (poison z) produce tiny garbage
// that is multiplied by nm=0 in the epilogue.
// -------------------------------------------------------------------------
#define BM 64
#define BN 64
#define BK 64

__global__ __launch_bounds__(256)
void k_node_mlp(const float* __restrict__ h, const unsigned short* __restrict__ z,
                const float* __restrict__ node_mask,
                const float* __restrict__ wW, const float* __restrict__ wb,
                float* __restrict__ out)
{
    __shared__ short As[BM][72];
    __shared__ short Bs[BN][72];
    __shared__ float nm_lds[BM];
    __shared__ float wb_lds[BN];
    const int tid = threadIdx.x;
    const int mb  = blockIdx.x >> 3;         // 32 row-blocks
    const int nb  = blockIdx.x & 7;          // 8 col-blocks
    const int m0  = mb * BM, n0 = nb * BN;

    if (tid < BM)                nm_lds[tid]      = node_mask[m0 + tid];
    else if (tid < BM + BN)      wb_lds[tid - BM] = wb[n0 + (tid - BM)];

    const int lane = tid & 63;
    const int wv   = tid >> 6;
    const int wr   = wv >> 1, wc = wv & 1;   // wave quadrant (wr*32, wc*32)
    const int fr   = lane & 15;              // fragment row/col
    const int fk   = (lane >> 4) * 8;        // fragment k-offset

    f32x4 acc[2][2] = {};

    for (int ks = 0; ks < 2 * CH; ks += BK) {
        #pragma unroll
        for (int q = 0; q < 2; ++q) {        // A: 64 rows x 8 chunks of 16B
            const int id = tid + q * 256;
            const int row = id >> 3, ck = id & 7;
            ushort8 v = *(const ushort8*)&z[(size_t)(m0 + row) * (2 * CH) + ks + ck * 8];
            *(ushort8*)&As[row][ck * 8] = v;
        }
        #pragma unroll
        for (int q = 0; q < 4; ++q) {        // B: 64 rows x 16 chunks of 4 f32, cvt->bf16
            const int id = tid + q * 256;
            const int row = id >> 4, ck = id & 15;
            float4 v = *(const float4*)&wW[(size_t)(n0 + row) * (2 * CH) + ks + ck * 4];
            ushort4_t o;
            o.x = f2bf(v.x); o.y = f2bf(v.y); o.z = f2bf(v.z); o.w = f2bf(v.w);
            *(ushort4_t*)&Bs[row][ck * 4] = o;
        }
        __syncthreads();
        #pragma unroll
        for (int kk = 0; kk < BK; kk += 32) {
            bf16x8 a0 = *(const bf16x8*)&As[wr * 32 +      fr][kk + fk];
            bf16x8 a1 = *(const bf16x8*)&As[wr * 32 + 16 + fr][kk + fk];
            bf16x8 bb0 = *(const bf16x8*)&Bs[wc * 32 +      fr][kk + fk];
            bf16x8 bb1 = *(const bf16x8*)&Bs[wc * 32 + 16 + fr][kk + fk];
            acc[0][0] = __builtin_amdgcn_mfma_f32_16x16x32_bf16(a0, bb0, acc[0][0], 0, 0, 0);
            acc[0][1] = __builtin_amdgcn_mfma_f32_16x16x32_bf16(a0, bb1, acc[0][1], 0, 0, 0);
            acc[1][0] = __builtin_amdgcn_mfma_f32_16x16x32_bf16(a1, bb0, acc[1][0], 0, 0, 0);
            acc[1][1] = __builtin_amdgcn_mfma_f32_16x16x32_bf16(a1, bb1, acc[1][1], 0, 0, 0);
        }
        __syncthreads();
    }

    // epilogue: C/D layout col=lane&15, row=(lane>>4)*4+reg
    #pragma unroll
    for (int mt = 0; mt < 2; ++mt) {
        #pragma unroll
        for (int nt = 0; nt < 2; ++nt) {
            #pragma unroll
            for (int q = 0; q < 4; ++q) {
                const int r = wr * 32 + mt * 16 + (lane >> 4) * 4 + q;
                const int c = wc * 32 + nt * 16 + fr;
                const size_t gi = (size_t)(m0 + r) * CH + (n0 + c);
                float v = acc[mt][nt][q] + wb_lds[c];
                v = selu_f(v) * nm_lds[r];
                out[gi] = v + h[gi];
            }
        }
    }
}

extern "C" void kernel_launch(void* const* d_in, const int* in_sizes, int n_in,
                              void* d_out, int out_size, void* d_ws, size_t ws_size,
                              hipStream_t stream)
{
    (void)in_sizes; (void)n_in; (void)out_size; (void)ws_size;
    const float* h  = (const float*)d_in[0];
    const float* e  = (const float*)d_in[1];
    const float* nm = (const float*)d_in[2];
    const float* em = (const float*)d_in[3];
    const float* fW = (const float*)d_in[4];
    const float* fb = (const float*)d_in[5];
    const float* wW = (const float*)d_in[6];
    const float* wb = (const float*)d_in[7];
    float* out = (float*)d_out;
    unsigned short* z = (unsigned short*)d_ws;   // 2048 x 1024 bf16 = 4 MB

    k_edge_agg<<<NBATCH * (NA / 2), 256, 0, stream>>>(h, e, nm, em, fW, fb, z);
    k_node_mlp<<<(NBATCH * NA / BM) * (CH / BN), 256, 0, stream>>>(h, z, nm, wW, wb, out);
}

// Round 4
// 179.891 us; speedup vs baseline: 2.3364x; 1.3921x over previous
//
#include <hip/hip_runtime.h>
#include <hip/hip_bf16.h>
#include <math.h>

#define NBATCH 16
#define NA     128
#define CH     512
#define EFEAT  30

typedef __attribute__((ext_vector_type(8))) short          bf16x8;
typedef __attribute__((ext_vector_type(4))) float          f32x4;
typedef __attribute__((ext_vector_type(8))) unsigned short ushort8;
typedef __attribute__((ext_vector_type(4))) unsigned short ushort4_t;

__device__ __forceinline__ float selu_f(float x) {
    // selu: 1.0507*x (x>0) else 1.7581*(e^x - 1); exp vs expm1 abs err ~1e-7.
    const float SA = 1.7580993408473766f;
    float e = __expf(x);
    return x > 0.0f ? 1.0507009873554805f * x : fmaf(SA, e, -SA);
}

__device__ __forceinline__ unsigned short f2bf(float f) {
    __hip_bfloat16 h = __float2bfloat16(f);   // RNE
    return *reinterpret_cast<unsigned short*>(&h);
}

// -------------------------------------------------------------------------
// Kernel 1: edge filter + SELU + edge-mask + aggregation, MFMA formulation.
// Per live (b,i) row:  S[c,j] = fW[c,:30] · e[b,i,j,:30]   (bf16 MFMA, K=32 pad)
//   h1[c] = sum_j selu(S[c,j]+fb[c]) * em[j] * h[b,j,c]
// A-operand = fW rows (m=c), held in registers (8 frags/wave, loaded once).
// B-operand = e row (n=j), staged bf16 in LDS (stride 40 -> 2-way-free banks).
// D layout: col=lane&15=j, row=(lane>>4)*4+q=c  =>  per lane the 4 c's are
// consecutive -> h is ONE float4 load; j-reduction = shfl_xor{1,2,4,8}.
// One __syncthreads per block; dead node_mask rows exit immediately.
// Emits z[row] = [bf16(h row) | bf16(h1)] for kernel 2.
// -------------------------------------------------------------------------
__global__ __launch_bounds__(256, 4)
void k_edge_mfma(const float* __restrict__ h, const float* __restrict__ e,
                 const float* __restrict__ node_mask, const float* __restrict__ edge_mask,
                 const float* __restrict__ fW, const float* __restrict__ fb,
                 unsigned short* __restrict__ z)
{
    __shared__ unsigned short e_lds[NA * 40];   // [128][40] bf16, k padded 30->32
    __shared__ float em_lds[NA];
    __shared__ float fb_lds[CH];

    const int row = blockIdx.x;                 // (b*128 + i), 2048 blocks
    if (node_mask[row] == 0.0f) return;         // uniform early-exit
    const int b = row >> 7;

    const int tid  = threadIdx.x;
    const int lane = tid & 63;
    const int wv   = tid >> 6;
    const int s    = lane & 15;                 // fragment col (j within tile)
    const int g    = lane >> 4;                 // k-group / row-group
    const int cbase = wv * 128;                 // wave owns 128 channels

    // stage fb
    for (int idx = tid; idx < CH; idx += 256) fb_lds[idx] = fb[idx];
    // stage edge mask row
    if (tid < NA) em_lds[tid] = edge_mask[(size_t)row * NA + tid];
    // stage e row -> bf16 [128][40], pad k 30..31 with zeros
    const float* esrc = e + (size_t)row * (NA * EFEAT);
    for (int idx = tid; idx < NA * 32; idx += 256) {
        const int j = idx >> 5, f = idx & 31;
        const float v = (f < EFEAT) ? esrc[j * EFEAT + f] : 0.0f;
        e_lds[j * 40 + f] = f2bf(v);
    }

    // A-fragments: fW rows (c), loaded once from global f32 + cvt.
    // lane holds A[c = cbase+cf*16+s][k = g*8+e8]
    bf16x8 afrag[8];
    #pragma unroll
    for (int cf = 0; cf < 8; ++cf) {
        const int c = cbase + cf * 16 + s;
        const float* wrow = fW + (size_t)c * EFEAT;
        ushort8 t;
        #pragma unroll
        for (int e8 = 0; e8 < 8; ++e8) {
            const int k = g * 8 + e8;
            t[e8] = (k < EFEAT) ? f2bf(wrow[k]) : (unsigned short)0;
        }
        afrag[cf] = *(bf16x8*)&t;
    }

    __syncthreads();

    f32x4 acc[8];
    #pragma unroll
    for (int cf = 0; cf < 8; ++cf) acc[cf] = (f32x4){0.f, 0.f, 0.f, 0.f};

    #pragma unroll 2
    for (int jt = 0; jt < 8; ++jt) {
        const int j = jt * 16 + s;                       // this lane's j
        const bf16x8 bfrag = *(const bf16x8*)&e_lds[j * 40 + g * 8];
        const float  emj   = em_lds[j];
        const float* hbase = h + ((size_t)(b * NA) + j) * CH;
        #pragma unroll
        for (int cf = 0; cf < 8; ++cf) {
            f32x4 S = __builtin_amdgcn_mfma_f32_16x16x32_bf16(
                          afrag[cf], bfrag, (f32x4){0.f, 0.f, 0.f, 0.f}, 0, 0, 0);
            const int c0 = cbase + cf * 16 + g * 4;      // 4 consecutive c
            const f32x4 hv = *(const f32x4*)&hbase[c0];
            const f32x4 bv = *(const f32x4*)&fb_lds[c0];
            #pragma unroll
            for (int q = 0; q < 4; ++q) {
                const float sv = selu_f(S[q] + bv[q]);
                acc[cf][q] = fmaf(emj, sv * hv[q], acc[cf][q]);  // em in {0,1}
            }
        }
    }

    // reduce over j (across the 16 lanes of each column group)
    #pragma unroll
    for (int m = 1; m <= 8; m <<= 1) {
        #pragma unroll
        for (int cf = 0; cf < 8; ++cf) {
            #pragma unroll
            for (int q = 0; q < 4; ++q)
                acc[cf][q] += __shfl_xor(acc[cf][q], m, 64);
        }
    }

    // emit z row: [bf16(h) | bf16(h1)]
    unsigned short* zrow = z + (size_t)row * (2 * CH);
    const float* hrow = h + (size_t)row * CH;
    zrow[tid]       = f2bf(hrow[tid]);
    zrow[tid + 256] = f2bf(hrow[tid + 256]);
    if (s == 0) {                                // lanes 0,16,32,48 hold sums
        #pragma unroll
        for (int cf = 0; cf < 8; ++cf) {
            const int c0 = cbase + cf * 16 + g * 4;
            ushort4_t o;
            #pragma unroll
            for (int q = 0; q < 4; ++q) o[q] = f2bf(acc[cf][q]);
            *(ushort4_t*)&zrow[CH + c0] = o;
        }
    }
}

// -------------------------------------------------------------------------
// Kernel 2: node MLP bf16 MFMA GEMM, barrier-free direct-load K-loop.
// C = z(2048x1024 bf16) @ wW^T(512x1024 f32, cvt in regs); epilogue
// out = selu(C + wb)*nm + h. 64x64 tile, 256 blocks, 4 waves = 2x2 quadrants.
// A/B fragments loaded straight global->VGPR (L2-resident), no LDS, no
// __syncthreads -> compiler freely pipelines 24+ loads across unroll-4.
// Dead z rows are 0xAA poison; nm=0 masks them in the epilogue.
// -------------------------------------------------------------------------
__global__ __launch_bounds__(256, 4)
void k_node_mlp(const float* __restrict__ h, const unsigned short* __restrict__ z,
                const float* __restrict__ node_mask,
                const float* __restrict__ wW, const float* __restrict__ wb,
                float* __restrict__ out)
{
    const int tid  = threadIdx.x;
    const int lane = tid & 63;
    const int wv   = tid >> 6;
    const int wr   = wv >> 1, wc = wv & 1;
    const int s    = lane & 15, g = lane >> 4;
    const int m0   = (blockIdx.x >> 3) * 64;
    const int n0   = (blockIdx.x & 7) * 64;

    const unsigned short* zA0 = z  + (size_t)(m0 + wr * 32 +      s) * (2 * CH) + g * 8;
    const unsigned short* zA1 = z  + (size_t)(m0 + wr * 32 + 16 + s) * (2 * CH) + g * 8;
    const float*          wB0 = wW + (size_t)(n0 + wc * 32 +      s) * (2 * CH) + g * 8;
    const float*          wB1 = wW + (size_t)(n0 + wc * 32 + 16 + s) * (2 * CH) + g * 8;

    f32x4 acc[2][2] = {};

    #pragma unroll 4
    for (int ks = 0; ks < 2 * CH; ks += 32) {
        const bf16x8 a0 = *(const bf16x8*)&zA0[ks];
        const bf16x8 a1 = *(const bf16x8*)&zA1[ks];
        const f32x4 u00 = *(const f32x4*)&wB0[ks];
        const f32x4 u01 = *(const f32x4*)&wB0[ks + 4];
        const f32x4 u10 = *(const f32x4*)&wB1[ks];
        const f32x4 u11 = *(const f32x4*)&wB1[ks + 4];
        ushort8 t0, t1;
        #pragma unroll
        for (int q = 0; q < 4; ++q) {
            t0[q]     = f2bf(u00[q]);
            t0[q + 4] = f2bf(u01[q]);
            t1[q]     = f2bf(u10[q]);
            t1[q + 4] = f2bf(u11[q]);
        }
        const bf16x8 b0 = *(bf16x8*)&t0;
        const bf16x8 b1 = *(bf16x8*)&t1;
        acc[0][0] = __builtin_amdgcn_mfma_f32_16x16x32_bf16(a0, b0, acc[0][0], 0, 0, 0);
        acc[0][1] = __builtin_amdgcn_mfma_f32_16x16x32_bf16(a0, b1, acc[0][1], 0, 0, 0);
        acc[1][0] = __builtin_amdgcn_mfma_f32_16x16x32_bf16(a1, b0, acc[1][0], 0, 0, 0);
        acc[1][1] = __builtin_amdgcn_mfma_f32_16x16x32_bf16(a1, b1, acc[1][1], 0, 0, 0);
    }

    // epilogue: D col = s (n), row = g*4+q (m)
    #pragma unroll
    for (int mt = 0; mt < 2; ++mt) {
        const int rbase = m0 + wr * 32 + mt * 16 + g * 4;
        const f32x4 nmv = *(const f32x4*)&node_mask[rbase];
        #pragma unroll
        for (int nt = 0; nt < 2; ++nt) {
            const int c = n0 + wc * 32 + nt * 16 + s;
            const float wbv = wb[c];
            #pragma unroll
            for (int q = 0; q < 4; ++q) {
                const size_t gi = (size_t)(rbase + q) * CH + c;
                const float v = selu_f(acc[mt][nt][q] + wbv) * nmv[q];
                out[gi] = v + h[gi];
            }
        }
    }
}

extern "C" void kernel_launch(void* const* d_in, const int* in_sizes, int n_in,
                              void* d_out, int out_size, void* d_ws, size_t ws_size,
                              hipStream_t stream)
{
    (void)in_sizes; (void)n_in; (void)out_size; (void)ws_size;
    const float* h  = (const float*)d_in[0];
    const float* e  = (const float*)d_in[1];
    const float* nm = (const float*)d_in[2];
    const float* em = (const float*)d_in[3];
    const float* fW = (const float*)d_in[4];
    const float* fb = (const float*)d_in[5];
    const float* wW = (const float*)d_in[6];
    const float* wb = (const float*)d_in[7];
    float* out = (float*)d_out;
    unsigned short* z = (unsigned short*)d_ws;   // 2048 x 1024 bf16 = 4 MB

    k_edge_mfma<<<NBATCH * NA, 256, 0, stream>>>(h, e, nm, em, fW, fb, z);
    k_node_mlp<<<(NBATCH * NA / 64) * (CH / 64), 256, 0, stream>>>(h, z, nm, wW, wb, out);
}

// Round 6
// 137.642 us; speedup vs baseline: 3.0536x; 1.3069x over previous
//
#include <hip/hip_runtime.h>
#include <hip/hip_bf16.h>
#include <math.h>

#define NBATCH 16
#define NA     128
#define CH     512
#define EFEAT  30

typedef __attribute__((ext_vector_type(8))) short          bf16x8;
typedef __attribute__((ext_vector_type(4))) float          f32x4;
typedef __attribute__((ext_vector_type(8))) unsigned short ushort8;
typedef __attribute__((ext_vector_type(4))) unsigned short ushort4_t;

__device__ __forceinline__ float selu_f(float x) {
    const float SA = 1.7580993408473766f;     // scale*alpha
    float e = __expf(x);
    return x > 0.0f ? 1.0507009873554805f * x : fmaf(SA, e, -SA);
}

__device__ __forceinline__ unsigned short f2bf(float f) {
    __hip_bfloat16 h = __float2bfloat16(f);   // RNE
    return *reinterpret_cast<unsigned short*>(&h);
}

// -------------------------------------------------------------------------
// Kernel 1: edge filter + SELU + mask + aggregation (MFMA, live-j compacted).
// Per live (b,i):  S[c,p] = fW[c,:30]·e[b,i,jlist[p],:30] + fb[c]
//                  (bias folded: e k=30 slot = 1.0, afrag k=30 slot = fb[c])
//   h1[c] = sum_{p<nlive} selu(S[c,p]) * h[b,jlist[p],c]
// Live j's ballot-compacted -> only live e rows staged/computed (~2x less).
// A-frags (fW+fb) in registers; e row bf16 in LDS (stride 40 -> benign banks).
// D layout: col=lane&15=p, row=(lane>>4)*4+q=c -> h is one float4/lane;
// j-reduce = shfl_xor{1,2,4,8}. hv[8] prefetch block issues 8 global loads
// ahead of the selu chain. jlist is re-read from LDS per tile (broadcast,
// conflict-free) instead of a runtime-indexed register array (rule #20:
// that would lower to scratch). XCD-swizzled blockIdx shares the h panel.
// -------------------------------------------------------------------------
__global__ __launch_bounds__(256, 4)
void k_edge_mfma(const float* __restrict__ h, const float* __restrict__ e,
                 const float* __restrict__ node_mask, const float* __restrict__ edge_mask,
                 const float* __restrict__ fW, const float* __restrict__ fb,
                 unsigned short* __restrict__ z)
{
    __shared__ unsigned short e_lds[NA * 40];   // [<=128][40] bf16, k 30->32 (k30=1.0)
    __shared__ int   jlist[NA];
    __shared__ int   wcnt[2];

    const int row = (blockIdx.x & 7) * 256 + (blockIdx.x >> 3);  // XCD swizzle, 2048=8*256
    if (node_mask[row] == 0.0f) return;          // block-uniform early exit
    const int b = row >> 7;

    const int tid  = threadIdx.x;
    const int lane = tid & 63;
    const int wv   = tid >> 6;
    const int s    = lane & 15;                  // fragment col (compact p)
    const int g    = lane >> 4;                  // k-group / row-group
    const int cbase = wv * 128;                  // wave owns 128 channels

    // ballot-compact live j (edge_mask is exactly 0 or 1)
    float myq = 0.0f; unsigned long long bl = 0;
    if (tid < NA) {
        myq = edge_mask[(size_t)row * NA + tid];
        bl = __ballot(myq != 0.0f);
        if ((tid & 63) == 0) wcnt[tid >> 6] = __popcll(bl);
    }
    __syncthreads();                             // wcnt ready
    const int nlive  = wcnt[0] + wcnt[1];
    const int ntiles = (nlive + 15) >> 4;
    if (tid < NA) {
        if (myq != 0.0f) {
            const int base = (tid >= 64) ? wcnt[0] : 0;
            const int pos  = __popcll(bl & ((1ull << (tid & 63)) - 1));
            jlist[base + pos] = tid;
        }
        if (tid >= nlive) jlist[tid] = 0;        // pads (disjoint slots)
    }
    __syncthreads();                             // jlist ready

    // A-fragments: fW rows + bias in k=30 slot.  lane: c=cbase+cf*16+s, k=g*8+e8
    bf16x8 afrag[8];
    #pragma unroll
    for (int cf = 0; cf < 8; ++cf) {
        const int c = cbase + cf * 16 + s;
        const float* wrow = fW + (size_t)c * EFEAT;
        ushort8 t;
        #pragma unroll
        for (int e8 = 0; e8 < 8; ++e8) {
            const int k = g * 8 + e8;
            const float v = (k < EFEAT) ? wrow[k] : (k == EFEAT ? fb[c] : 0.0f);
            t[e8] = f2bf(v);
        }
        afrag[cf] = *(bf16x8*)&t;
    }

    // stage compacted e rows -> bf16 LDS; pad rows zeroed (avoid stale NaN)
    const float* esrc = e + (size_t)row * (NA * EFEAT);
    const int npad = ntiles * 16;
    for (int idx = tid; idx < npad * 32; idx += 256) {
        const int p = idx >> 5, f = idx & 31;
        float v = 0.0f;
        if (p < nlive) {
            const int j = jlist[p];
            v = (f < EFEAT) ? esrc[j * EFEAT + f] : (f == EFEAT ? 1.0f : 0.0f);
        }
        e_lds[p * 40 + f] = f2bf(v);
    }

    // z-row echo of h (independent of main loop; issue early)
    unsigned short* zrow = z + (size_t)row * (2 * CH);
    const float* hrow = h + (size_t)row * CH;
    zrow[tid]       = f2bf(hrow[tid]);
    zrow[tid + 256] = f2bf(hrow[tid + 256]);

    __syncthreads();                             // e_lds ready

    f32x4 acc[8];
    #pragma unroll
    for (int cf = 0; cf < 8; ++cf) acc[cf] = (f32x4){0.f, 0.f, 0.f, 0.f};

    #pragma unroll 2
    for (int jt = 0; jt < ntiles; ++jt) {
        const int   p   = jt * 16 + s;
        const float emj = (p < nlive) ? 1.0f : 0.0f;     // pad gate
        const int   jj  = jlist[p];                      // LDS broadcast read
        const bf16x8 bfrag = *(const bf16x8*)&e_lds[p * 40 + g * 8];
        const float* hbase = h + ((size_t)(b * NA) + jj) * CH;
        f32x4 hv[8];
        #pragma unroll
        for (int cf = 0; cf < 8; ++cf)           // 8 independent loads in flight
            hv[cf] = *(const f32x4*)&hbase[cbase + cf * 16 + g * 4];
        #pragma unroll
        for (int cf = 0; cf < 8; ++cf) {
            f32x4 S = __builtin_amdgcn_mfma_f32_16x16x32_bf16(
                          afrag[cf], bfrag, (f32x4){0.f, 0.f, 0.f, 0.f}, 0, 0, 0);
            #pragma unroll
            for (int q = 0; q < 4; ++q) {
                const float sv = selu_f(S[q]);           // bias already in S
                acc[cf][q] = fmaf(emj, sv * hv[cf][q], acc[cf][q]);
            }
        }
    }

    // reduce over compact p across the 16 s-lanes of each g-group
    #pragma unroll
    for (int m = 1; m <= 8; m <<= 1)
        #pragma unroll
        for (int cf = 0; cf < 8; ++cf)
            #pragma unroll
            for (int q = 0; q < 4; ++q)
                acc[cf][q] += __shfl_xor(acc[cf][q], m, 64);

    if (s == 0) {                                // lanes 0,16,32,48 hold sums
        #pragma unroll
        for (int cf = 0; cf < 8; ++cf) {
            const int c0 = cbase + cf * 16 + g * 4;
            ushort4_t o;
            #pragma unroll
            for (int q = 0; q < 4; ++q) o[q] = f2bf(acc[cf][q]);
            *(ushort4_t*)&zrow[CH + c0] = o;
        }
    }
}

// -------------------------------------------------------------------------
// Kernel 2: node MLP bf16 MFMA GEMM, occupancy-first structure.
// C = z(2048x1024 bf16) @ wW^T; out = selu(C+wb)*nm + h.
// 32x32 tiles, BK=128 -> grid 1024 (4 blocks/CU, 16 waves/CU). Both operands
// LDS-staged (rows padded to 136 shorts -> 2-way-free ds_read_b128); wW
// f32->bf16 converted during reg-staging. 4 waves = 2x2 16x16 quadrants,
// 8 K-steps x 4 MFMA. XCD swizzle: 128-block chunks share the 2MB wW panel.
// Dead z rows are 0xAA poison (tiny bf16 values, no NaN); nm=0 masks them.
// -------------------------------------------------------------------------
__global__ __launch_bounds__(256, 4)
void k_node_mlp(const float* __restrict__ h, const unsigned short* __restrict__ z,
                const float* __restrict__ node_mask,
                const float* __restrict__ wW, const float* __restrict__ wb,
                float* __restrict__ out)
{
    __shared__ short As[32][136];
    __shared__ short Bs[32][136];
    const int tid = threadIdx.x;
    const int bid = (blockIdx.x & 7) * 128 + (blockIdx.x >> 3);  // 1024 = 8*128
    const int m0  = (bid >> 4) * 32;
    const int n0  = (bid & 15) * 32;
    const int lane = tid & 63, wv = tid >> 6;
    const int wr = wv >> 1, wc = wv & 1;
    const int s  = lane & 15, g = lane >> 4;

    const int arow = tid >> 3;                   // staging: 8 threads/row
    const int akb  = (tid & 7) * 16;             // 16 elems each

    f32x4 acc = {0.f, 0.f, 0.f, 0.f};

    for (int ks = 0; ks < 2 * CH; ks += 128) {
        // A: z tile (bf16 passthrough)
        const ushort8 a0 = *(const ushort8*)&z[(size_t)(m0 + arow) * (2 * CH) + ks + akb];
        const ushort8 a1 = *(const ushort8*)&z[(size_t)(m0 + arow) * (2 * CH) + ks + akb + 8];
        // B: wW tile f32 -> bf16
        const float* wsrc = wW + (size_t)(n0 + arow) * (2 * CH) + ks + akb;
        const f32x4 u0 = *(const f32x4*)&wsrc[0];
        const f32x4 u1 = *(const f32x4*)&wsrc[4];
        const f32x4 u2 = *(const f32x4*)&wsrc[8];
        const f32x4 u3 = *(const f32x4*)&wsrc[12];
        ushort8 t0, t1;
        #pragma unroll
        for (int q = 0; q < 4; ++q) {
            t0[q] = f2bf(u0[q]); t0[q + 4] = f2bf(u1[q]);
            t1[q] = f2bf(u2[q]); t1[q + 4] = f2bf(u3[q]);
        }
        *(ushort8*)&As[arow][akb]     = a0;
        *(ushort8*)&As[arow][akb + 8] = a1;
        *(ushort8*)&Bs[arow][akb]     = t0;
        *(ushort8*)&Bs[arow][akb + 8] = t1;
        __syncthreads();
        #pragma unroll
        for (int kk = 0; kk < 128; kk += 32) {
            const bf16x8 af = *(const bf16x8*)&As[wr * 16 + s][kk + g * 8];
            const bf16x8 bf = *(const bf16x8*)&Bs[wc * 16 + s][kk + g * 8];
            acc = __builtin_amdgcn_mfma_f32_16x16x32_bf16(af, bf, acc, 0, 0, 0);
        }
        __syncthreads();
    }

    // epilogue: D col=s (n), row=g*4+q (m)
    const int r0 = m0 + wr * 16 + g * 4;
    const int c  = n0 + wc * 16 + s;
    const float wbv = wb[c];
    const f32x4 nmv = *(const f32x4*)&node_mask[r0];
    #pragma unroll
    for (int q = 0; q < 4; ++q) {
        const size_t gi = (size_t)(r0 + q) * CH + c;
        out[gi] = selu_f(acc[q] + wbv) * nmv[q] + h[gi];
    }
}

extern "C" void kernel_launch(void* const* d_in, const int* in_sizes, int n_in,
                              void* d_out, int out_size, void* d_ws, size_t ws_size,
                              hipStream_t stream)
{
    (void)in_sizes; (void)n_in; (void)out_size; (void)ws_size;
    const float* h  = (const float*)d_in[0];
    const float* e  = (const float*)d_in[1];
    const float* nm = (const float*)d_in[2];
    const float* em = (const float*)d_in[3];
    const float* fW = (const float*)d_in[4];
    const float* fb = (const float*)d_in[5];
    const float* wW = (const float*)d_in[6];
    const float* wb = (const float*)d_in[7];
    float* out = (float*)d_out;
    unsigned short* z = (unsigned short*)d_ws;   // 2048 x 1024 bf16 = 4 MB

    k_edge_mfma<<<NBATCH * NA, 256, 0, stream>>>(h, e, nm, em, fW, fb, z);
    k_node_mlp<<<(NBATCH * NA / 32) * (CH / 32), 256, 0, stream>>>(h, z, nm, wW, wb, out);
}